// Round 3
// baseline (199.031 us; speedup 1.0000x reference)
//
#include <hip/hip_runtime.h>

// Problem constants (from reference)
#define C_IN    7
#define NKER    586
#define KH      8
#define SEQ     4096
#define T_LEN   (SEQ * 3)      // 12288 gathered positions
#define HP      (T_LEN + 1)    // 12289 output positions
#define NC      4096           // output channels (7*585 + 1)
#define KO_N    585            // kernels per g-channel for the main block

#define H_TILE  32             // 64 -> 32: grid (4,385)=1540 blocks = 6 blocks/CU
#define BLOCK   256
#define CPT     4              // channels per thread (float4 store)
#define C_PER_BLOCK (BLOCK * CPT)   // 1024
#define GROW    (H_TILE + 7)   // g values needed per channel per tile (39)

#define TAPS_LD  9                   // padded leading dim (q*9+k) -> 8-way max on readback
#define TAP_CNT  (NKER * KH)         // 4688 staged taps

__global__ __launch_bounds__(BLOCK) void conv1d_gather_kernel(
    const float* __restrict__ x,      // (SEQ, C_IN)
    const float* __restrict__ kern,   // (NKER, KH, 3)
    float* __restrict__ out)          // flat[h*NC + c]
{
    __shared__ float g[C_IN][GROW + 1];          // +1 pad
    __shared__ float tap_lds[NKER * TAPS_LD];    // 586*9 floats = 21.1 KB

    const int h0  = blockIdx.y * H_TILE;
    const int c0  = blockIdx.x * C_PER_BLOCK;
    const int tid = threadIdx.x;

    // ---- Stage ALL middle-column taps coalesced: tap_lds[q*9+k] = kern[q,k,1] ----
    for (int i = tid; i < TAP_CNT; i += BLOCK) {
        tap_lds[i + (i >> 3)] = kern[i * 3 + 1];
    }

    // ---- Stage g[ci][tt] for t = h0-4 .. h0+H_TILE+2 (zero outside [0,T_LEN)) ----
    const int GCNT = C_IN * GROW;  // 273
    for (int i = tid; i < GCNT; i += BLOCK) {
        int ci = i / GROW;
        int tt = i - ci * GROW;
        int t  = h0 - 4 + tt;
        float v = 0.0f;
        if (t >= 0 && t < T_LEN) {
            int s  = t / 3;
            int j  = t - 3 * s;
            int si = s + j;
            si = (si > SEQ - 1) ? (SEQ - 1) : si;
            v = x[si * C_IN + ci];
        }
        g[ci][tt] = v;
    }
    __syncthreads();

    const int cbase = c0 + tid * CPT;    // multiple of 4, never 4095

    // ---- Per-channel kernel index + g-channel selection (static per thread) ----
    float taps[CPT][KH];
    int   gci[CPT];
    #pragma unroll
    for (int j = 0; j < CPT; j++) {
        int c = cbase + j;
        int gc, kidx;
        if (c == NC - 1) { gc = 0; kidx = NKER - 1; }   // last row: g[0] * kernels[585]
        else             { gc = c / KO_N; kidx = c - KO_N * gc; }
        gci[j] = gc;
        #pragma unroll
        for (int k = 0; k < KH; k++)
            taps[j][k] = tap_lds[kidx * TAPS_LD + k];   // LDS readback
    }

    // ---- One sliding window PER channel, bound to its g row once ----
    float win[CPT][KH];
    #pragma unroll
    for (int j = 0; j < CPT; j++)
        #pragma unroll
        for (int k = 0; k < KH; k++)
            win[j][k] = g[gci[j]][k];

    int hend = HP - h0; if (hend > H_TILE) hend = H_TILE;
    float* outp = out + (size_t)h0 * NC + cbase;

    auto body = [&](int nrows) {
        #pragma unroll 8
        for (int hh = 0; hh < nrows; hh++) {
            float d[CPT];
            #pragma unroll
            for (int j = 0; j < CPT; j++) d[j] = 0.0f;
            #pragma unroll
            for (int k = 0; k < KH; k++) {
                #pragma unroll
                for (int j = 0; j < CPT; j++)
                    d[j] = fmaf(win[j][k], taps[j][k], d[j]);
            }
            float4 o;
            o.x = d[0]; o.y = d[1]; o.z = d[2]; o.w = d[3];
            *reinterpret_cast<float4*>(outp) = o;
            outp += NC;

            // slide each window by one position (register renames under unroll)
            #pragma unroll
            for (int k = 0; k < KH - 1; k++) {
                #pragma unroll
                for (int j = 0; j < CPT; j++)
                    win[j][k] = win[j][k + 1];
            }
            #pragma unroll
            for (int j = 0; j < CPT; j++)
                win[j][KH - 1] = g[gci[j]][hh + KH];
        }
    };

    if (hend == H_TILE) body(H_TILE);   // compile-time trip count for the hot path
    else                body(hend);     // only the last row-tile (hend == 1)
}

extern "C" void kernel_launch(void* const* d_in, const int* in_sizes, int n_in,
                              void* d_out, int out_size, void* d_ws, size_t ws_size,
                              hipStream_t stream) {
    const float* x    = (const float*)d_in[0];   // (1, 4096, 7, 1) f32
    const float* kern = (const float*)d_in[1];   // (586, 8, 3) f32
    float* out        = (float*)d_out;           // 12289*4096 f32

    dim3 grid(NC / C_PER_BLOCK, (HP + H_TILE - 1) / H_TILE);  // (4, 385)
    conv1d_gather_kernel<<<grid, BLOCK, 0, stream>>>(x, kern, out);
}

// Round 4
// 194.946 us; speedup vs baseline: 1.0210x; 1.0210x over previous
//
#include <hip/hip_runtime.h>

// Problem constants (from reference)
#define C_IN    7
#define NKER    586
#define KH      8
#define SEQ     4096
#define T_LEN   (SEQ * 3)      // 12288 gathered positions
#define HP      (T_LEN + 1)    // 12289 output positions
#define NC      4096           // output channels (7*585 + 1)
#define KO_N    585            // kernels per g-channel for the main block

#define H_TILE  64             // R2's proven best: grid (4,193), 3 blocks/CU
#define BLOCK   256
#define CPT     4              // channels per thread (float4 store)
#define C_PER_BLOCK (BLOCK * CPT)   // 1024
#define GROW    (H_TILE + 7)   // g values needed per channel per tile (71)

#define TAPS_LD  9                   // padded leading dim -> 8-way max on readback
#define TAP_CNT  (NKER * KH)         // 4688 staged taps

// Hot path with COMPILE-TIME trip count: full unroll -> window slides become
// register renames (zero v_mov), g refills become ds_read base+offset:imm,
// store addresses fold to immediate offsets, 64 renamed stores max out the
// store queue. (R3 showed more WAVES don't hide the per-iter bubbles; more
// ILP within a wave is the remaining lever.)
template <int NR>
__device__ __forceinline__ void run_rows(
    const float (*g)[GROW + 1], const float taps[CPT][KH],
    const int gci[CPT], float* outp)
{
    float win[CPT][KH];
    #pragma unroll
    for (int j = 0; j < CPT; j++)
        #pragma unroll
        for (int k = 0; k < KH; k++)
            win[j][k] = g[gci[j]][k];

    #pragma unroll
    for (int hh = 0; hh < NR; hh++) {
        float d[CPT];
        #pragma unroll
        for (int j = 0; j < CPT; j++) d[j] = win[j][0] * taps[j][0];
        #pragma unroll
        for (int k = 1; k < KH; k++) {
            #pragma unroll
            for (int j = 0; j < CPT; j++)
                d[j] = fmaf(win[j][k], taps[j][k], d[j]);
        }
        float4 o;
        o.x = d[0]; o.y = d[1]; o.z = d[2]; o.w = d[3];
        *reinterpret_cast<float4*>(outp + (size_t)hh * NC) = o;

        #pragma unroll
        for (int k = 0; k < KH - 1; k++)
            #pragma unroll
            for (int j = 0; j < CPT; j++)
                win[j][k] = win[j][k + 1];
        #pragma unroll
        for (int j = 0; j < CPT; j++)
            win[j][KH - 1] = g[gci[j]][hh + KH];
    }
}

__global__ __launch_bounds__(BLOCK) void conv1d_gather_kernel(
    const float* __restrict__ x,      // (SEQ, C_IN)
    const float* __restrict__ kern,   // (NKER, KH, 3)
    float* __restrict__ out)          // flat[h*NC + c]
{
    __shared__ float g[C_IN][GROW + 1];          // +1 pad
    __shared__ float tap_lds[NKER * TAPS_LD];    // 586*9 floats = 21.1 KB

    const int h0  = blockIdx.y * H_TILE;
    const int c0  = blockIdx.x * C_PER_BLOCK;
    const int tid = threadIdx.x;

    // ---- Stage ALL middle-column taps coalesced: tap_lds[q*9+k] = kern[q,k,1] ----
    for (int i = tid; i < TAP_CNT; i += BLOCK) {
        tap_lds[i + (i >> 3)] = kern[i * 3 + 1];
    }

    // ---- Stage g[ci][tt] for t = h0-4 .. h0+H_TILE+2 (zero outside [0,T_LEN)) ----
    const int GCNT = C_IN * GROW;  // 497
    for (int i = tid; i < GCNT; i += BLOCK) {
        int ci = i / GROW;
        int tt = i - ci * GROW;
        int t  = h0 - 4 + tt;
        float v = 0.0f;
        if (t >= 0 && t < T_LEN) {
            int s  = t / 3;
            int j  = t - 3 * s;
            int si = s + j;
            si = (si > SEQ - 1) ? (SEQ - 1) : si;
            v = x[si * C_IN + ci];
        }
        g[ci][tt] = v;
    }
    __syncthreads();

    const int cbase = c0 + tid * CPT;    // multiple of 4, never 4095

    // ---- Per-channel kernel index + g-channel selection (static per thread) ----
    float taps[CPT][KH];
    int   gci[CPT];
    #pragma unroll
    for (int j = 0; j < CPT; j++) {
        int c = cbase + j;
        int gc, kidx;
        if (c == NC - 1) { gc = 0; kidx = NKER - 1; }   // last row: g[0] * kernels[585]
        else             { gc = c / KO_N; kidx = c - KO_N * gc; }
        gci[j] = gc;
        #pragma unroll
        for (int k = 0; k < KH; k++)
            taps[j][k] = tap_lds[kidx * TAPS_LD + k];   // LDS readback
    }

    const int hend = HP - h0;
    float* outp = out + (size_t)h0 * NC + cbase;

    if (hend >= H_TILE) {
        run_rows<H_TILE>(g, taps, gci, outp);     // hot path, full unroll
    } else {
        // tail tile (only h0 = 12288, hend == 1)
        float win[CPT][KH];
        #pragma unroll
        for (int j = 0; j < CPT; j++)
            #pragma unroll
            for (int k = 0; k < KH; k++)
                win[j][k] = g[gci[j]][k];
        for (int hh = 0; hh < hend; hh++) {
            float d[CPT];
            #pragma unroll
            for (int j = 0; j < CPT; j++) d[j] = win[j][0] * taps[j][0];
            #pragma unroll
            for (int k = 1; k < KH; k++)
                #pragma unroll
                for (int j = 0; j < CPT; j++)
                    d[j] = fmaf(win[j][k], taps[j][k], d[j]);
            float4 o;
            o.x = d[0]; o.y = d[1]; o.z = d[2]; o.w = d[3];
            *reinterpret_cast<float4*>(outp + (size_t)hh * NC) = o;
            #pragma unroll
            for (int k = 0; k < KH - 1; k++)
                #pragma unroll
                for (int j = 0; j < CPT; j++)
                    win[j][k] = win[j][k + 1];
            #pragma unroll
            for (int j = 0; j < CPT; j++)
                win[j][KH - 1] = g[gci[j]][hh + KH];
        }
    }
}

extern "C" void kernel_launch(void* const* d_in, const int* in_sizes, int n_in,
                              void* d_out, int out_size, void* d_ws, size_t ws_size,
                              hipStream_t stream) {
    const float* x    = (const float*)d_in[0];   // (1, 4096, 7, 1) f32
    const float* kern = (const float*)d_in[1];   // (586, 8, 3) f32
    float* out        = (float*)d_out;           // 12289*4096 f32

    dim3 grid(NC / C_PER_BLOCK, (HP + H_TILE - 1) / H_TILE);  // (4, 193)
    conv1d_gather_kernel<<<grid, BLOCK, 0, stream>>>(x, kern, out);
}